// Round 12
// baseline (284.488 us; speedup 1.0000x reference)
//
#include <hip/hip_runtime.h>

typedef __bf16 bf16_t;
typedef __attribute__((ext_vector_type(8))) __bf16 bf16x8;
typedef __attribute__((ext_vector_type(4))) __bf16 bf16x4;
typedef __attribute__((ext_vector_type(4))) float f32x4;

// async global->LDS, 16B per lane; LDS dest = wave-uniform base + lane*16
#define GLL16(gsrc, ldst) __builtin_amdgcn_global_load_lds( \
    (const __attribute__((address_space(1))) void*)(gsrc),  \
    (__attribute__((address_space(3))) void*)(ldst), 16, 0, 0)
#define SBAR() __builtin_amdgcn_s_barrier()
#define SCHED0() __builtin_amdgcn_sched_barrier(0)

// ---------------- dtype detect: 1 = bf16 inputs, 0 = fp32 inputs.
__global__ void detect_dtype(const unsigned short* __restrict__ ct, int* __restrict__ flag) {
    if (threadIdx.x == 0 && blockIdx.x == 0) {
        int ok = 1;
        for (int i = 0; i < 16; i++) {
            int e = (ct[256 + i] >> 7) & 0xFF;
            ok &= (e >= 80 && e <= 126) ? 1 : 0;
        }
        *flag = ok;
    }
}

// ---------------- merged prep: conv_op + ctb + 4x pack_w (NO swizzle) + scan_rows
// pack: [K][N] -> [K/32][N][32] bf16 (wave-private staging de-swizzles via per-lane src)
__global__ void prep(const void* __restrict__ op_table, bf16_t* __restrict__ opb,
                     const void* __restrict__ comp_table, bf16_t* __restrict__ ctb,
                     const void* __restrict__ W1b, bf16_t* __restrict__ W1bp,
                     const void* __restrict__ W1t, bf16_t* __restrict__ W1tp,
                     const void* __restrict__ W2b, bf16_t* __restrict__ W2bp,
                     const void* __restrict__ W2t, bf16_t* __restrict__ W2tp,
                     const int* __restrict__ flagp,
                     const int* __restrict__ lvl2, const int* __restrict__ lvl1,
                     const int* __restrict__ lvl0, const int* __restrict__ third,
                     int* __restrict__ lists, int* __restrict__ cnts,
                     int* __restrict__ inv) {
    int b = blockIdx.x, tid = threadIdx.x;
    if (b >= 6624) {
        int r = (b - 6624) * 256 + tid;   // covers exactly 28672
        int slot, lr, base_t, base_b;
        const int* lvl;
        if (r < 16384)      { slot = 0; lr = r;         lvl = lvl2; base_t = 0;     base_b = 16384; }
        else if (r < 24576) { slot = 1; lr = r - 16384; lvl = lvl1; base_t = 32768; base_b = 40960; }
        else                { slot = 2; lr = r - 24576; lvl = lvl0; base_t = 49152; base_b = 53248; }
        int node = lvl[lr];
        int tern = third[node] >= 0 ? 1 : 0;
        if (slot == 0)      inv[node] = lr;
        else if (slot == 1) inv[node] = 16384 + lr;

        unsigned long long bt = __ballot(tern);
        unsigned long long bb = __ballot(!tern);
        int lane = tid & 63;
        unsigned long long ltm = (1ull << lane) - 1ull;
        int post = __popcll(bt & ltm), posb = __popcll(bb & ltm);
        int baseT = 0, baseB = 0;
        if (lane == 0) {
            baseT = atomicAdd(&cnts[slot * 2 + 1], __popcll(bt));
            baseB = atomicAdd(&cnts[slot * 2 + 0], __popcll(bb));
        }
        baseT = __shfl(baseT, 0, 64);
        baseB = __shfl(baseB, 0, 64);
        lists[tern ? (base_t + baseT + post) : (base_b + baseB + posb)] = lr;
        return;
    }
    int isbf = *flagp;
    if (b < 16) {
        int i = b * 256 + tid;
        opb[i] = isbf ? ((const bf16_t*)op_table)[i] : (bf16_t)((const float*)op_table)[i];
        return;
    }
    if (b < 2016) {
        int i = (b - 16) * 256 + tid;
        ctb[i] = isbf ? ((const bf16_t*)comp_table)[i] : (bf16_t)((const float*)comp_table)[i];
        return;
    }
    const void* src; bf16_t* dst; int e0, Nmask, Nshift;
    if (b < 3552)      { src = W1b; dst = W1bp; e0 = (b - 2016) * 256; Nmask = 511; Nshift = 9; }
    else if (b < 5600) { src = W1t; dst = W1tp; e0 = (b - 3552) * 256; Nmask = 511; Nshift = 9; }
    else if (b < 6112) { src = W2b; dst = W2bp; e0 = (b - 5600) * 256; Nmask = 255; Nshift = 8; }
    else               { src = W2t; dst = W2tp; e0 = (b - 6112) * 256; Nmask = 255; Nshift = 8; }
    int e = e0 + tid;
    bf16_t v = isbf ? ((const bf16_t*)src)[e] : (bf16_t)((const float*)src)[e];
    int n = e & Nmask, k = e >> Nshift;
    dst[(size_t)((((k >> 5) << Nshift) + n) * 32 + (k & 31))] = v;
}

__device__ __forceinline__ void load8f(const bf16_t* ne2, const void* ct, int isbf,
                                       int invn, int cidn, int q, float* o) {
    if (invn >= 0) {
        bf16x8 v = *(const bf16x8*)(ne2 + (size_t)invn * 256 + q);
        for (int z = 0; z < 8; z++) o[z] = (float)v[z];
    } else if (isbf) {
        bf16x8 v = *(const bf16x8*)((const bf16_t*)ct + (size_t)cidn * 256 + q);
        for (int z = 0; z < 8; z++) o[z] = (float)v[z];
    } else {
        const float* fp = (const float*)ct + (size_t)cidn * 256 + q;
        f32x4 a = *(const f32x4*)fp, b = *(const f32x4*)(fp + 4);
        for (int z = 0; z < 4; z++) { o[z] = a[z]; o[z + 4] = b[z]; }
    }
}

__device__ __forceinline__ float ldparam(const void* p, int i, int isbf) {
    return isbf ? (float)((const bf16_t*)p)[i] : ((const float*)p)[i];
}

// ---------------- fused level kernel, M=32, 512 threads, 2 blocks/CU
// BARRIERLESS K-loops: B slabs staged wave-private (GLL16, per-wave vmcnt);
// A fragments loaded per-lane global->reg with 1-iter prefetch (unroll x2).
// Barriers only at GEMM1->H and H->GEMM2 boundaries + epilogue.
// LDS map (68096 B):
//   GEMM1: B1 wave-private dbuf: wave w at [w*8K, w*8K+8K) = 2 x 4KB  -> [0,64K)
//   GELU/GEMM2: H [32][512] bf16 swizzled at [0,32K);
//               B2 wave-private dbuf: wave w at [32K + w*4K, +4K) = 2 x 2KB
//   epilogue: R float[32][256] at [0,32K); LN partials at [64K,66.5K)
__global__ __launch_bounds__(512, 2) void fused_level(
    const int* __restrict__ list_t, const int* __restrict__ list_b,
    const int* __restrict__ cntpair, const int* __restrict__ lvl_idx,
    const int* __restrict__ op_ids, const int* __restrict__ lch,
    const int* __restrict__ rch, const int* __restrict__ tch,
    bf16_t* __restrict__ ne2, const bf16_t* __restrict__ opb,
    const void* __restrict__ ct, const bf16_t* __restrict__ ctb,
    const int* __restrict__ cid, const int* __restrict__ inv,
    const int* __restrict__ flagp,
    const bf16_t* __restrict__ W1tp, const void* __restrict__ b1t,
    const bf16_t* __restrict__ W2tp, const void* __restrict__ b2t,
    const bf16_t* __restrict__ W1bp, const void* __restrict__ b1b,
    const bf16_t* __restrict__ W2bp, const void* __restrict__ b2b,
    const void* __restrict__ gma, const void* __restrict__ bta,
    int slotBase, void* __restrict__ out)
{
    __shared__ __align__(1024) char smem[68096];

    const int tid = threadIdx.x;
    const int w = tid >> 6, lane = tid & 63, cc = lane & 15, qq = lane >> 4;
    const int e7 = cc & 7;          // chunk XOR for H
    const int cnt_t = cntpair[1], cnt_b = cntpair[0];
    const int blocks_t = (cnt_t + 31) >> 5;
    int tern, base, cnt, K1c;
    const int* list;
    const bf16_t *W1p, *W2p;
    const void *b1, *b2;
    if ((int)blockIdx.x < blocks_t) {
        tern = 1; list = list_t; base = blockIdx.x * 32; cnt = cnt_t;
        W1p = W1tp; b1 = b1t; W2p = W2tp; b2 = b2t; K1c = 32;
    } else {
        tern = 0; list = list_b; base = (blockIdx.x - blocks_t) * 32; cnt = cnt_b;
        if (base >= cnt) return;
        W1p = W1bp; b1 = b1b; W2p = W2bp; b2 = b2b; K1c = 24;
    }
    const int act = min(32, cnt - base);
    const int isbf = *flagp;

    // ---- per-lane A-row source pointers for rows m*16+cc (m=0,1)
    const bf16_t *a0p0, *a0p1, *a0p2, *a0p3, *a1p0, *a1p1, *a1p2, *a1p3;
    {
        int r0 = cc, r1 = 16 + cc;
        int lr0 = list[base + min(r0, act - 1)];
        int nd0 = lvl_idx[lr0];
        a0p0 = opb + (size_t)op_ids[nd0] * 256;
        int x0 = lch[nd0], x1 = rch[nd0];
        int x2 = tern ? tch[nd0] : x0;
        int i0 = inv[x0], i1 = inv[x1], i2 = inv[x2];
        a0p1 = i0 >= 0 ? ne2 + (size_t)i0 * 256 : ctb + (size_t)cid[x0] * 256;
        a0p2 = i1 >= 0 ? ne2 + (size_t)i1 * 256 : ctb + (size_t)cid[x1] * 256;
        a0p3 = i2 >= 0 ? ne2 + (size_t)i2 * 256 : ctb + (size_t)cid[x2] * 256;
        int lr1 = list[base + min(r1, act - 1)];
        int nd1 = lvl_idx[lr1];
        a1p0 = opb + (size_t)op_ids[nd1] * 256;
        int y0 = lch[nd1], y1 = rch[nd1];
        int y2 = tern ? tch[nd1] : y0;
        int j0 = inv[y0], j1 = inv[y1], j2 = inv[y2];
        a1p1 = j0 >= 0 ? ne2 + (size_t)j0 * 256 : ctb + (size_t)cid[y0] * 256;
        a1p2 = j1 >= 0 ? ne2 + (size_t)j1 * 256 : ctb + (size_t)cid[y1] * 256;
        a1p3 = j2 >= 0 ? ne2 + (size_t)j2 * 256 : ctb + (size_t)cid[y2] * 256;
    }

    // ---- residual identity: row ms = tid>>4, col group gs = tid&15
    const int ms = tid >> 4, gs = tid & 15;
    const int lr = list[base + min(ms, act - 1)];
    const int node = lvl_idx[lr];
    const int c0 = lch[node], c1 = rch[node];
    const int c2 = tern ? tch[node] : c0;
    int sInv[3] = {inv[c0], inv[c1], inv[c2]};
    int sCid[3];
    sCid[0] = sInv[0] < 0 ? cid[c0] : 0;
    sCid[1] = sInv[1] < 0 ? cid[c1] : 0;
    sCid[2] = sInv[2] < 0 ? cid[c2] : 0;

    // per-lane params for GEMM2 epilogue: cols (w+8j)*16+cc, j=0..1
    float b2f[2], gf[2], btf[2];
    for (int j = 0; j < 2; j++) {
        int col = (w + 8 * j) * 16 + cc;
        b2f[j] = ldparam(b2, col, isbf);
        gf[j] = ldparam(gma, col, isbf);
        btf[j] = ldparam(bta, col, isbf);
    }

    // ---- wave-private staging identities
    const int nrowB1 = (w + 8 * (lane >> 4)) * 16 + (lane & 15);  // B1 row this lane stages
    const int r2 = lane & 31;
    const int nrowB2 = (w + 8 * (r2 >> 4)) * 16 + (r2 & 15);      // B2 row this lane stages
    const int i2base = lane >> 5;                                  // 0 or 1

    // B1 wave-private stage: 4KB slab = 64 rows x 64B; lane stages its row's 4 chunks
#define STAGE1(kc_, sel_) do {                                                     \
        const char* s_ = (const char*)W1p + ((size_t)(kc_) << 15) + nrowB1 * 64;   \
        char* d_ = smem + (w << 13) + ((sel_) << 12);                              \
        GLL16(s_,      d_);                                                        \
        GLL16(s_ + 16, d_ + 1024);                                                 \
        GLL16(s_ + 32, d_ + 2048);                                                 \
        GLL16(s_ + 48, d_ + 3072);                                                 \
    } while (0)
    // B2 wave-private stage: 2KB slab = 32 rows x 64B
#define STAGE2(kc_, sel_) do {                                                     \
        const char* s_ = (const char*)W2p + ((size_t)(kc_) << 14)                  \
                         + nrowB2 * 64 + i2base * 16;                              \
        char* d_ = smem + 32768 + (w << 12) + ((sel_) << 11);                      \
        GLL16(s_,      d_);                                                        \
        GLL16(s_ + 32, d_ + 1024);                                                 \
    } while (0)
    // per-lane A fragment (global->reg): rows m*16+cc, cols kc*32+qq*8..+8
#define AFLOAD(kc_, f0_, f1_) do {                                                 \
        int colg_ = (kc_) * 32 + qq * 8;                                           \
        int piece_ = colg_ >> 8, po_ = colg_ & 255;                                \
        const bf16_t* s0_ = piece_ == 0 ? a0p0 : piece_ == 1 ? a0p1                \
                          : piece_ == 2 ? a0p2 : a0p3;                             \
        const bf16_t* s1_ = piece_ == 0 ? a1p0 : piece_ == 1 ? a1p1                \
                          : piece_ == 2 ? a1p2 : a1p3;                             \
        f0_ = *(const bf16x8*)(s0_ + po_);                                         \
        f1_ = *(const bf16x8*)(s1_ + po_);                                         \
    } while (0)

    const f32x4 zf = {0.f, 0.f, 0.f, 0.f};
    f32x4 acc1[2][4];
    for (int m = 0; m < 2; m++) for (int j = 0; j < 4; j++) acc1[m][j] = zf;

    // ================= GEMM1: barrierless, wave-private dbuf + reg-prefetched A ========
    bf16x8 afA0, afA1, afB0, afB1;
    STAGE1(0, 0);
    AFLOAD(0, afA0, afA1);
    for (int kc = 0; kc < K1c; kc += 2) {
        { // even step: consume sel=0 + afA; prefetch kc+1 -> sel=1, afB
            int kn = kc + 1 < K1c ? kc + 1 : K1c - 1;
            STAGE1(kn, 1);
            AFLOAD(kn, afB0, afB1);
            asm volatile("s_waitcnt vmcnt(6)" ::: "memory");
            SCHED0();
            const char* bs = smem + (w << 13);
            __builtin_amdgcn_s_setprio(1);
            for (int j = 0; j < 4; j++) {
                bf16x8 bv = *(const bf16x8*)(bs + (qq << 10) + ((j * 16 + cc) << 4));
                acc1[0][j] = __builtin_amdgcn_mfma_f32_16x16x32_bf16(bv, afA0, acc1[0][j], 0, 0, 0);
                acc1[1][j] = __builtin_amdgcn_mfma_f32_16x16x32_bf16(bv, afA1, acc1[1][j], 0, 0, 0);
            }
            __builtin_amdgcn_s_setprio(0);
        }
        { // odd step: consume sel=1 + afB; prefetch kc+2 -> sel=0, afA
            int kn = kc + 2 < K1c ? kc + 2 : K1c - 1;
            STAGE1(kn, 0);
            AFLOAD(kn, afA0, afA1);
            asm volatile("s_waitcnt vmcnt(6)" ::: "memory");
            SCHED0();
            const char* bs = smem + (w << 13) + 4096;
            __builtin_amdgcn_s_setprio(1);
            for (int j = 0; j < 4; j++) {
                bf16x8 bv = *(const bf16x8*)(bs + (qq << 10) + ((j * 16 + cc) << 4));
                acc1[0][j] = __builtin_amdgcn_mfma_f32_16x16x32_bf16(bv, afB0, acc1[0][j], 0, 0, 0);
                acc1[1][j] = __builtin_amdgcn_mfma_f32_16x16x32_bf16(bv, afB1, acc1[1][j], 0, 0, 0);
            }
            __builtin_amdgcn_s_setprio(0);
        }
    }
    asm volatile("s_waitcnt vmcnt(0)" ::: "memory");
    SCHED0();
    SBAR();                         // all waves done with B1 regions

    // ================= H write (GELU) + B2 slab 0 prefetch =================
    STAGE2(0, 0);
    {
        unsigned short* Hs = (unsigned short*)smem;
        for (int j = 0; j < 4; j++) {
            float b1q[4];
            for (int r = 0; r < 4; r++) b1q[r] = ldparam(b1, (w + 8 * j) * 16 + qq * 4 + r, isbf);
            int c16 = ((w + 8 * j) << 1) + (qq >> 1);
            for (int m = 0; m < 2; m++) {
                int row = m * 16 + cc;
                bf16x4 hv;
                for (int r = 0; r < 4; r++) {
                    float v = acc1[m][j][r] + b1q[r];
                    hv[r] = (bf16_t)(0.5f * v * (1.0f + erff(v * 0.70710678118654752f)));
                }
                *(bf16x4*)(Hs + (row << 9) + ((c16 ^ e7) << 3) + ((qq & 1) << 2)) = hv;
            }
        }
    }
    asm volatile("s_waitcnt vmcnt(0) lgkmcnt(0)" ::: "memory");
    SCHED0();
    SBAR();                         // H visible to all; B2(0) landed

    // ================= GEMM2: barrierless, wave-private dbuf =================
    f32x4 acc2[2][2];
    for (int m = 0; m < 2; m++) for (int j = 0; j < 2; j++) acc2[m][j] = zf;
    for (int kc = 0; kc < 16; kc++) {
        const int sel = kc & 1;
        const int kn = kc + 1 < 16 ? kc + 1 : 15;
        STAGE2(kn, sel ^ 1);
        asm volatile("s_waitcnt vmcnt(2)" ::: "memory");
        SCHED0();
        const unsigned short* Hs = (const unsigned short*)smem;
        const char* b2s = smem + 32768 + (w << 12) + (sel << 11);
        bf16x8 af[2];
        for (int m = 0; m < 2; m++)
            af[m] = *(const bf16x8*)(Hs + ((m * 16 + cc) << 9) + ((((kc << 2) + qq) ^ e7) << 3));
        __builtin_amdgcn_s_setprio(1);
        for (int j = 0; j < 2; j++) {
            bf16x8 bv = *(const bf16x8*)(b2s + (qq << 9) + ((j * 16 + cc) << 4));
            for (int m = 0; m < 2; m++)
                acc2[m][j] = __builtin_amdgcn_mfma_f32_16x16x32_bf16(af[m], bv, acc2[m][j], 0, 0, 0);
        }
        __builtin_amdgcn_s_setprio(0);
    }
    asm volatile("s_waitcnt vmcnt(0)" ::: "memory");
    __syncthreads();                // all waves done reading H / B2

    // ---------- residual gather -> R float[32][256] at smem[0,32K)
    {
        float* Rf = (float*)smem;
        int colb = gs * 16;
        for (int i = 0; i < 2; i++) {
            int q = colb + i * 8;
            float lv[8], rv[8], tv[8];
            load8f(ne2, ct, isbf, sInv[0], sCid[0], q, lv);
            load8f(ne2, ct, isbf, sInv[1], sCid[1], q, rv);
            if (tern) load8f(ne2, ct, isbf, sInv[2], sCid[2], q, tv);
            f32x4 s0, s1;
            if (tern) {
                for (int z = 0; z < 4; z++) {
                    s0[z] = (lv[z] + rv[z] + tv[z]) * (1.0f / 3.0f);
                    s1[z] = (lv[z + 4] + rv[z + 4] + tv[z + 4]) * (1.0f / 3.0f);
                }
            } else {
                for (int z = 0; z < 4; z++) {
                    s0[z] = lv[z] + rv[z];
                    s1[z] = lv[z + 4] + rv[z + 4];
                }
            }
            *(f32x4*)(Rf + ms * 256 + q) = s0;
            *(f32x4*)(Rf + ms * 256 + q + 4) = s1;
        }
    }
    __syncthreads();

    // ---------- x = gemm2 + b2 + R ; LayerNorm over 256 cols per row
    float* partS = (float*)(smem + 65536); // [8][32]
    float* partQ = partS + 256;            // [8][32]
    float* muA   = partQ + 256;            // [32]
    float* rsA   = muA + 32;               // [32]
    const float* Rf = (const float*)smem;

    for (int m = 0; m < 2; m++) for (int r = 0; r < 4; r++) {
        int row = m * 16 + qq * 4 + r;
        float ps = 0.f, pq = 0.f;
        for (int j = 0; j < 2; j++) {
            int col = (w + 8 * j) * 16 + cc;
            float x = acc2[m][j][r] + b2f[j] + Rf[(row << 8) + col];
            acc2[m][j][r] = x;
            ps += x; pq += x * x;
        }
        for (int d = 1; d < 16; d <<= 1) {
            ps += __shfl_xor(ps, d, 64);
            pq += __shfl_xor(pq, d, 64);
        }
        if (cc == 0) { partS[w * 32 + row] = ps; partQ[w * 32 + row] = pq; }
    }
    __syncthreads();
    if (tid < 32) {
        float s = 0.f, sq = 0.f;
        for (int i = 0; i < 8; i++) {
            s  += partS[i * 32 + tid];
            sq += partQ[i * 32 + tid];
        }
        float mu = s * (1.0f / 256.0f);
        float var = sq * (1.0f / 256.0f) - mu * mu;
        muA[tid] = mu;
        rsA[tid] = rsqrtf(fmaxf(var, 0.0f) + 1e-5f);
    }
    __syncthreads();

    for (int m = 0; m < 2; m++) for (int r = 0; r < 4; r++) {
        int row = m * 16 + qq * 4 + r;
        if (row >= act) continue;
        float mu = muA[row], rs = rsA[row];
        int lr2 = list[base + row];
        for (int j = 0; j < 2; j++) {
            int col = (w + 8 * j) * 16 + cc;
            float y = (acc2[m][j][r] - mu) * rs * gf[j] + btf[j];
            if (out) {
                if (isbf) ((bf16_t*)out)[(size_t)lr2 * 256 + col] = (bf16_t)y;
                else      ((float*)out)[(size_t)lr2 * 256 + col] = y;
            } else {
                ne2[(size_t)(slotBase + lr2) * 256 + col] = (bf16_t)y;
            }
        }
    }
#undef STAGE1
#undef STAGE2
#undef AFLOAD
}

extern "C" void kernel_launch(void* const* d_in, const int* in_sizes, int n_in,
                              void* d_out, int out_size, void* d_ws, size_t ws_size,
                              hipStream_t stream) {
    const int* cid    = (const int*)d_in[0];
    const int* opids  = (const int*)d_in[1];
    const int* lch    = (const int*)d_in[2];
    const int* rch    = (const int*)d_in[3];
    const int* tch    = (const int*)d_in[4];
    const int* lvl2   = (const int*)d_in[5];
    const int* lvl1   = (const int*)d_in[6];
    const int* lvl0   = (const int*)d_in[7];
    const void* comp_table = d_in[8];
    const void* op_table   = d_in[9];
    const void* W1b = d_in[10];
    const void* b1b = d_in[11];
    const void* W2b = d_in[12];
    const void* b2b = d_in[13];
    const void* W1t = d_in[14];
    const void* b1t = d_in[15];
    const void* W2t = d_in[16];
    const void* b2t = d_in[17];
    const void* gma = d_in[18];
    const void* bta = d_in[19];

    char* wsp = (char*)d_ws;
    bf16_t* ne2  = (bf16_t*)wsp;                 size_t off = 12582912; // 24576*256*2
    bf16_t* opb  = (bf16_t*)(wsp + off);         off += 8192;           // 16*256*2
    bf16_t* ctb  = (bf16_t*)(wsp + off);         off += 1024000;        // 2000*256*2
    bf16_t* W1bp = (bf16_t*)(wsp + off);         off += 786432;         // 768*512*2
    bf16_t* W1tp = (bf16_t*)(wsp + off);         off += 1048576;        // 1024*512*2
    bf16_t* W2bp = (bf16_t*)(wsp + off);         off += 262144;         // 512*256*2
    bf16_t* W2tp = (bf16_t*)(wsp + off);         off += 262144;
    int* inv   = (int*)(wsp + off);              off += 262144;         // 65536*4
    int* lists = (int*)(wsp + off);              off += 229376;         // 57344*4
    int* cnts  = (int*)(wsp + off);              off += 64;             // total ~16.5 MB
    int* flag  = cnts + 8;

    hipMemsetAsync(cnts, 0, 64, stream);
    hipMemsetAsync(inv, 0xFF, 262144, stream);
    detect_dtype<<<1, 64, 0, stream>>>((const unsigned short*)comp_table, flag);
    // one merged prep dispatch: conv_op + ctb + pack_w x4 + scan_rows
    prep<<<6736, 256, 0, stream>>>(op_table, opb, comp_table, ctb,
                                   W1b, W1bp, W1t, W1tp, W2b, W2bp, W2t, W2tp, flag,
                                   lvl2, lvl1, lvl0, tch, lists, cnts, inv);

    // level 2: lists t @0 / b @16384, cnts slot 0 -> slots base 0
    fused_level<<<513, 512, 0, stream>>>(lists + 0, lists + 16384, cnts + 0, lvl2,
        opids, lch, rch, tch, ne2, opb, comp_table, ctb, cid, inv, flag,
        W1tp, b1t, W2tp, b2t, W1bp, b1b, W2bp, b2b, gma, bta, 0, nullptr);
    // level 1: lists t @32768 / b @40960, cnts slot 1 -> slots base 16384
    fused_level<<<257, 512, 0, stream>>>(lists + 32768, lists + 40960, cnts + 2, lvl1,
        opids, lch, rch, tch, ne2, opb, comp_table, ctb, cid, inv, flag,
        W1tp, b1t, W2tp, b2t, W1bp, b1b, W2bp, b2b, gma, bta, 16384, nullptr);
    // level 0: lists t @49152 / b @53248, cnts slot 2 -> d_out
    fused_level<<<129, 512, 0, stream>>>(lists + 49152, lists + 53248, cnts + 4, lvl0,
        opids, lch, rch, tch, ne2, opb, comp_table, ctb, cid, inv, flag,
        W1tp, b1t, W2tp, b2t, W1bp, b1b, W2bp, b2b, gma, bta, 0, d_out);
}

// Round 13
// 213.364 us; speedup vs baseline: 1.3333x; 1.3333x over previous
//
#include <hip/hip_runtime.h>

typedef __bf16 bf16_t;
typedef __attribute__((ext_vector_type(8))) __bf16 bf16x8;
typedef __attribute__((ext_vector_type(4))) __bf16 bf16x4;
typedef __attribute__((ext_vector_type(4))) float f32x4;

// async global->LDS, 16B per lane; LDS dest = wave-uniform base + lane*16
#define GLL16(gsrc, ldst) __builtin_amdgcn_global_load_lds( \
    (const __attribute__((address_space(1))) void*)(gsrc),  \
    (__attribute__((address_space(3))) void*)(ldst), 16, 0, 0)
#define SBAR() __builtin_amdgcn_s_barrier()
#define SCHED0() __builtin_amdgcn_sched_barrier(0)

// ---------------- merged prep: detect + conv_op + ctb + 4x pack_w(swizzled) + scan_rows
// Output-major, 8 elems/thread. Blocks:
//   [0,2): op_table->bf16       [2,252): comp_table->ctb
//   [252,444): W1b pack  [444,700): W1t  [700,764): W2b  [764,828): W2t
//   [828,940): scan_rows
// pack: [K][N] -> [K/32][N][32] bf16 with 16B-chunk swizzle gp = (kl>>3)^((n>>1)&3).
// Each thread writes ONE 16B dst chunk (kc,n,gp): values src[kbase+i][n],
// kbase = kc*32 + (gp^((n>>1)&3))*8  — value-identical to the per-element pack.
__global__ void prep(const void* __restrict__ op_table, bf16_t* __restrict__ opb,
                     const void* __restrict__ comp_table, bf16_t* __restrict__ ctb,
                     const void* __restrict__ W1b, bf16_t* __restrict__ W1bp,
                     const void* __restrict__ W1t, bf16_t* __restrict__ W1tp,
                     const void* __restrict__ W2b, bf16_t* __restrict__ W2bp,
                     const void* __restrict__ W2t, bf16_t* __restrict__ W2tp,
                     int* __restrict__ flag,
                     const int* __restrict__ lvl2, const int* __restrict__ lvl1,
                     const int* __restrict__ lvl0, const int* __restrict__ third,
                     int* __restrict__ lists, int* __restrict__ cnts,
                     int* __restrict__ inv) {
    int b = blockIdx.x, tid = threadIdx.x;
    if (b >= 828) {
        // ---- scan: wave-aggregated partition (R0-verified math)
        int r = (b - 828) * 256 + tid;   // covers exactly 28672
        int slot, lr, base_t, base_b;
        const int* lvl;
        if (r < 16384)      { slot = 0; lr = r;         lvl = lvl2; base_t = 0;     base_b = 16384; }
        else if (r < 24576) { slot = 1; lr = r - 16384; lvl = lvl1; base_t = 32768; base_b = 40960; }
        else                { slot = 2; lr = r - 24576; lvl = lvl0; base_t = 49152; base_b = 53248; }
        int node = lvl[lr];
        int tern = third[node] >= 0 ? 1 : 0;
        if (slot == 0)      inv[node] = lr;
        else if (slot == 1) inv[node] = 16384 + lr;

        unsigned long long bt = __ballot(tern);
        unsigned long long bb = __ballot(!tern);
        int lane = tid & 63;
        unsigned long long ltm = (1ull << lane) - 1ull;
        int post = __popcll(bt & ltm), posb = __popcll(bb & ltm);
        int baseT = 0, baseB = 0;
        if (lane == 0) {
            baseT = atomicAdd(&cnts[slot * 2 + 1], __popcll(bt));
            baseB = atomicAdd(&cnts[slot * 2 + 0], __popcll(bb));
        }
        baseT = __shfl(baseT, 0, 64);
        baseB = __shfl(baseB, 0, 64);
        lists[tern ? (base_t + baseT + post) : (base_b + baseB + posb)] = lr;
        return;
    }
    // ---- dtype detect, computed locally per block (wave-uniform broadcast loads)
    int isbf;
    {
        const unsigned short* cts = (const unsigned short*)comp_table;
        int ok = 1;
        for (int i = 0; i < 16; i++) {
            int e = (cts[256 + i] >> 7) & 0xFF;
            ok &= (e >= 80 && e <= 126) ? 1 : 0;
        }
        isbf = ok;
    }
    if (b == 0 && tid == 0) *flag = isbf;   // published for fused_level (later dispatch)

    if (b < 252) {  // op (b<2) and ctb copies, 8 elems/thread
        int i0 = (b < 2) ? (b * 256 + tid) * 8 : ((b - 2) * 256 + tid) * 8;
        const void* s = (b < 2) ? op_table : comp_table;
        bf16_t* d = (b < 2) ? opb : ctb;
        if (isbf) {
            *(bf16x8*)(d + i0) = *(const bf16x8*)((const bf16_t*)s + i0);
        } else {
            const float* fp = (const float*)s + i0;
            bf16_t tmp[8];
            for (int z = 0; z < 8; z++) tmp[z] = (bf16_t)fp[z];
            *(bf16x8*)(d + i0) = *(bf16x8*)tmp;
        }
        return;
    }
    const void* src; bf16_t* dst; int c0_, Nshift;
    if (b < 444)      { src = W1b; dst = W1bp; c0_ = (b - 252) * 256; Nshift = 9; }
    else if (b < 700) { src = W1t; dst = W1tp; c0_ = (b - 444) * 256; Nshift = 9; }
    else if (b < 764) { src = W2b; dst = W2bp; c0_ = (b - 700) * 256; Nshift = 8; }
    else              { src = W2t; dst = W2tp; c0_ = (b - 764) * 256; Nshift = 8; }
    const int N = 1 << Nshift;
    int idx = c0_ + tid;                    // dst 16B-chunk index
    int kc  = idx >> (Nshift + 2);
    int rem = idx & ((N << 2) - 1);
    int gp  = rem >> Nshift;
    int n   = rem & (N - 1);
    int g_log = gp ^ ((n >> 1) & 3);
    int kbase = kc * 32 + g_log * 8;
    bf16_t tmp[8];
    if (isbf) {
        const bf16_t* sp = (const bf16_t*)src;
        for (int i = 0; i < 8; i++) tmp[i] = sp[((size_t)(kbase + i) << Nshift) + n];
    } else {
        const float* sp = (const float*)src;
        for (int i = 0; i < 8; i++) tmp[i] = (bf16_t)sp[((size_t)(kbase + i) << Nshift) + n];
    }
    *(bf16x8*)(dst + (size_t)(((kc << Nshift) + n) << 5) + (gp << 3)) = *(bf16x8*)tmp;
}

__device__ __forceinline__ void load8f(const bf16_t* ne2, const void* ct, int isbf,
                                       int invn, int cidn, int q, float* o) {
    if (invn >= 0) {
        bf16x8 v = *(const bf16x8*)(ne2 + (size_t)invn * 256 + q);
        for (int z = 0; z < 8; z++) o[z] = (float)v[z];
    } else if (isbf) {
        bf16x8 v = *(const bf16x8*)((const bf16_t*)ct + (size_t)cidn * 256 + q);
        for (int z = 0; z < 8; z++) o[z] = (float)v[z];
    } else {
        const float* fp = (const float*)ct + (size_t)cidn * 256 + q;
        f32x4 a = *(const f32x4*)fp, b = *(const f32x4*)(fp + 4);
        for (int z = 0; z < 4; z++) { o[z] = a[z]; o[z + 4] = b[z]; }
    }
}

__device__ __forceinline__ float ldparam(const void* p, int i, int isbf) {
    return isbf ? (float)((const bf16_t*)p)[i] : ((const float*)p)[i];
}

// ---------------- fused level kernel, M=32, 512 threads (8 waves), 2 blocks/CU
// R10 VERBATIM (best verified: 45.5us lvl2, WRITE 8.19MB, conflicts 1.18M).
// Counted-vmcnt dbuf pipeline; N-work split over 8 waves; acc1[2][4], acc2[2][2].
__global__ __launch_bounds__(512, 4) void fused_level(
    const int* __restrict__ list_t, const int* __restrict__ list_b,
    const int* __restrict__ cntpair, const int* __restrict__ lvl_idx,
    const int* __restrict__ op_ids, const int* __restrict__ lch,
    const int* __restrict__ rch, const int* __restrict__ tch,
    bf16_t* __restrict__ ne2, const bf16_t* __restrict__ opb,
    const void* __restrict__ ct, const bf16_t* __restrict__ ctb,
    const int* __restrict__ cid, const int* __restrict__ inv,
    const int* __restrict__ flagp,
    const bf16_t* __restrict__ W1tp, const void* __restrict__ b1t,
    const bf16_t* __restrict__ W2tp, const void* __restrict__ b2t,
    const bf16_t* __restrict__ W1bp, const void* __restrict__ b1b,
    const bf16_t* __restrict__ W2bp, const void* __restrict__ b2b,
    const void* __restrict__ gma, const void* __restrict__ bta,
    int slotBase, void* __restrict__ out)
{
    __shared__ __align__(1024) char smem[69632];

    const int tid = threadIdx.x;
    const int w = tid >> 6, lane = tid & 63, cc = lane & 15, qq = lane >> 4;
    const int gx = (cc >> 1) & 3;   // chunk XOR for packed-weight / A reads
    const int e7 = cc & 7;          // chunk XOR for H
    const int cnt_t = cntpair[1], cnt_b = cntpair[0];
    const int blocks_t = (cnt_t + 31) >> 5;
    int tern, base, cnt, K1c;
    const int* list;
    const bf16_t *W1p, *W2p;
    const void *b1, *b2;
    if ((int)blockIdx.x < blocks_t) {
        tern = 1; list = list_t; base = blockIdx.x * 32; cnt = cnt_t;
        W1p = W1tp; b1 = b1t; W2p = W2tp; b2 = b2t; K1c = 32;
    } else {
        tern = 0; list = list_b; base = (blockIdx.x - blocks_t) * 32; cnt = cnt_b;
        if (base >= cnt) return;
        W1p = W1bp; b1 = b1b; W2p = W2bp; b2 = b2b; K1c = 24;
    }
    const int act = min(32, cnt - base);
    const int isbf = *flagp;

    // ---- A-staging identity (tid<128 == waves 0,1): row = tid>>2, phys chunk = tid&3
    int glA = 0, opSA = 0;
    int aInv0 = 0, aInv1 = 0, aInv2 = 0, aCid0 = 0, aCid1 = 0, aCid2 = 0;
    if (tid < 128) {
        int rowA = tid >> 2;
        glA = (tid & 3) ^ ((rowA >> 1) & 3);        // logical chunk this thread fetches
        int rA = list[base + min(rowA, act - 1)];
        int nA = lvl_idx[rA];
        opSA = op_ids[nA];
        int a0 = lch[nA], a1 = rch[nA];
        int a2 = tern ? tch[nA] : a0;
        aInv0 = inv[a0]; aInv1 = inv[a1]; aInv2 = inv[a2];
        aCid0 = aInv0 < 0 ? cid[a0] : 0;
        aCid1 = aInv1 < 0 ? cid[a1] : 0;
        aCid2 = aInv2 < 0 ? cid[a2] : 0;
    }

    // ---- residual identity: row ms = tid>>4, col group gs = tid&15
    const int ms = tid >> 4, gs = tid & 15;
    const int lr = list[base + min(ms, act - 1)];
    const int node = lvl_idx[lr];
    const int c0 = lch[node], c1 = rch[node];
    const int c2 = tern ? tch[node] : c0;
    int sInv[3] = {inv[c0], inv[c1], inv[c2]};
    int sCid[3];
    sCid[0] = sInv[0] < 0 ? cid[c0] : 0;
    sCid[1] = sInv[1] < 0 ? cid[c1] : 0;
    sCid[2] = sInv[2] < 0 ? cid[c2] : 0;

    // per-lane params for GEMM2 epilogue: cols (w+8j)*16+cc, j=0..1
    float b2f[2], gf[2], btf[2];
    for (int j = 0; j < 2; j++) {
        int col = (w + 8 * j) * 16 + cc;
        b2f[j] = ldparam(b2, col, isbf);
        gf[j] = ldparam(gma, col, isbf);
        btf[j] = ldparam(bta, col, isbf);
    }

    const f32x4 zf = {0.f, 0.f, 0.f, 0.f};
    f32x4 acc1[2][4];
    for (int m = 0; m < 2; m++) for (int j = 0; j < 4; j++) acc1[m][j] = zf;

    // ================= GEMM1 (swapped operands), dbuf + counted vmcnt =================
    // B1 32KB = 2048 chunks; 512 threads x 4; A staged by waves 0,1.
#define STAGE1(kc_, bsel_) do {                                                   \
        const char* srcb_ = (const char*)W1p + ((size_t)(kc_) << 15);             \
        char* dstb_ = smem + ((bsel_) << 15);                                     \
        _Pragma("unroll")                                                         \
        for (int i_ = 0; i_ < 4; i_++) {                                          \
            int off_ = ((i_ << 3) + w) << 10;                                     \
            GLL16(srcb_ + off_ + (lane << 4), dstb_ + off_);                      \
        }                                                                         \
        if (w < 2) {                                                              \
            int colg_ = (kc_) * 32 + glA * 8;                                     \
            int piece_ = colg_ >> 8, po_ = colg_ & 255;                           \
            int iv_ = piece_ == 1 ? aInv0 : piece_ == 2 ? aInv1 : aInv2;          \
            int cd_ = piece_ == 1 ? aCid0 : piece_ == 2 ? aCid1 : aCid2;          \
            const bf16_t* s_ = piece_ == 0 ? opb + (size_t)opSA * 256             \
                : (iv_ >= 0 ? ne2 + (size_t)iv_ * 256 : ctb + (size_t)cd_ * 256); \
            GLL16(s_ + po_, smem + 65536 + ((bsel_) << 11) + (w << 10));          \
        }                                                                         \
    } while (0)

    STAGE1(0, 0);
    for (int kc = 0; kc < K1c; kc++) {
        const int cur = kc & 1;
        const bool more = kc + 1 < K1c;
        if (more) STAGE1(kc + 1, cur ^ 1);
        // wait: stage(kc) landed; stage(kc+1) (5 for waves 0-1, 4 for 2-7) in flight
        if (more) {
            if (w < 2) asm volatile("s_waitcnt vmcnt(5)" ::: "memory");
            else       asm volatile("s_waitcnt vmcnt(4)" ::: "memory");
        } else {
            asm volatile("s_waitcnt vmcnt(0)" ::: "memory");
        }
        SCHED0();
        SBAR();                     // buf[cur] complete for all waves
        SCHED0();
        const bf16_t* as = (const bf16_t*)(smem + 65536 + (cur << 11));
        const bf16_t* bs = (const bf16_t*)(smem + (cur << 15));
        bf16x8 af[2];
        for (int m = 0; m < 2; m++)
            af[m] = *(const bf16x8*)(as + (m * 16 + cc) * 32 + ((qq ^ gx) << 3));
        __builtin_amdgcn_s_setprio(1);
        for (int j = 0; j < 4; j++) {
            bf16x8 bv = *(const bf16x8*)(bs + ((w + 8 * j) * 16 + cc) * 32 + ((qq ^ gx) << 3));
            for (int m = 0; m < 2; m++)
                acc1[m][j] = __builtin_amdgcn_mfma_f32_16x16x32_bf16(bv, af[m], acc1[m][j], 0, 0, 0);
        }
        __builtin_amdgcn_s_setprio(0);
        SCHED0();
        SBAR();                     // all reads of buf[cur] done -> restageable
    }

    // ================= B2 slab 0 flies under bias + exact GELU -> H =================
#define STAGE2(kc_, bsel_) do {                                                   \
        const char* srcb_ = (const char*)W2p + ((size_t)(kc_) << 14);             \
        char* dstb_ = smem + ((bsel_) << 14);                                     \
        _Pragma("unroll")                                                         \
        for (int i_ = 0; i_ < 2; i_++) {                                          \
            int off_ = ((i_ << 3) + w) << 10;                                     \
            GLL16(srcb_ + off_ + (lane << 4), dstb_ + off_);                      \
        }                                                                         \
    } while (0)

    STAGE2(0, 0);
    {
        unsigned short* Hs = (unsigned short*)(smem + 32768);
        for (int j = 0; j < 4; j++) {
            float b1q[4];
            for (int r = 0; r < 4; r++) b1q[r] = ldparam(b1, (w + 8 * j) * 16 + qq * 4 + r, isbf);
            int c16 = ((w + 8 * j) << 1) + (qq >> 1);
            for (int m = 0; m < 2; m++) {
                int row = m * 16 + cc;
                bf16x4 hv;
                for (int r = 0; r < 4; r++) {
                    float v = acc1[m][j][r] + b1q[r];
                    hv[r] = (bf16_t)(0.5f * v * (1.0f + erff(v * 0.70710678118654752f)));
                }
                *(bf16x4*)(Hs + (row << 9) + ((c16 ^ e7) << 3) + ((qq & 1) << 2)) = hv;
            }
        }
    }

    // ================= GEMM2, dbuf + counted vmcnt =================
    f32x4 acc2[2][2];
    for (int m = 0; m < 2; m++) for (int j = 0; j < 2; j++) acc2[m][j] = zf;
    for (int kc = 0; kc < 16; kc++) {
        const int cur = kc & 1;
        const bool more = kc + 1 < 16;
        if (more) STAGE2(kc + 1, cur ^ 1);
        if (more) asm volatile("s_waitcnt vmcnt(2) lgkmcnt(0)" ::: "memory");
        else      asm volatile("s_waitcnt vmcnt(0) lgkmcnt(0)" ::: "memory");
        SCHED0();
        SBAR();
        SCHED0();
        const unsigned short* Hs = (const unsigned short*)(smem + 32768);
        const bf16_t* bs = (const bf16_t*)(smem + (cur << 14));
        bf16x8 af[2];
        for (int m = 0; m < 2; m++)
            af[m] = *(const bf16x8*)(Hs + ((m * 16 + cc) << 9) + ((((kc << 2) + qq) ^ e7) << 3));
        __builtin_amdgcn_s_setprio(1);
        for (int j = 0; j < 2; j++) {
            bf16x8 bv = *(const bf16x8*)(bs + ((w + 8 * j) * 16 + cc) * 32 + ((qq ^ gx) << 3));
            for (int m = 0; m < 2; m++)
                acc2[m][j] = __builtin_amdgcn_mfma_f32_16x16x32_bf16(af[m], bv, acc2[m][j], 0, 0, 0);
        }
        __builtin_amdgcn_s_setprio(0);
        SCHED0();
        SBAR();
    }
    __syncthreads();                // settle before epilogue overlays

    // ---------- residual gather -> R float[32][256] at smem[0,32K)
    {
        float* Rf = (float*)smem;
        int colb = gs * 16;
        for (int i = 0; i < 2; i++) {
            int q = colb + i * 8;
            float lv[8], rv[8], tv[8];
            load8f(ne2, ct, isbf, sInv[0], sCid[0], q, lv);
            load8f(ne2, ct, isbf, sInv[1], sCid[1], q, rv);
            if (tern) load8f(ne2, ct, isbf, sInv[2], sCid[2], q, tv);
            f32x4 s0, s1;
            if (tern) {
                for (int z = 0; z < 4; z++) {
                    s0[z] = (lv[z] + rv[z] + tv[z]) * (1.0f / 3.0f);
                    s1[z] = (lv[z + 4] + rv[z + 4] + tv[z + 4]) * (1.0f / 3.0f);
                }
            } else {
                for (int z = 0; z < 4; z++) {
                    s0[z] = lv[z] + rv[z];
                    s1[z] = lv[z + 4] + rv[z + 4];
                }
            }
            *(f32x4*)(Rf + ms * 256 + q) = s0;
            *(f32x4*)(Rf + ms * 256 + q + 4) = s1;
        }
    }
    __syncthreads();

    // ---------- x = gemm2 + b2 + R ; LayerNorm over 256 cols per row
    float* partS = (float*)(smem + 65536); // [8][32]
    float* partQ = partS + 256;            // [8][32]
    float* muA   = partQ + 256;            // [32]
    float* rsA   = muA + 32;               // [32]
    const float* Rf = (const float*)smem;

    for (int m = 0; m < 2; m++) for (int r = 0; r < 4; r++) {
        int row = m * 16 + qq * 4 + r;
        float ps = 0.f, pq = 0.f;
        for (int j = 0; j < 2; j++) {
            int col = (w + 8 * j) * 16 + cc;
            float x = acc2[m][j][r] + b2f[j] + Rf[(row << 8) + col];
            acc2[m][j][r] = x;
            ps += x; pq += x * x;
        }
        for (int d = 1; d < 16; d <<= 1) {
            ps += __shfl_xor(ps, d, 64);
            pq += __shfl_xor(pq, d, 64);
        }
        if (cc == 0) { partS[w * 32 + row] = ps; partQ[w * 32 + row] = pq; }
    }
    __syncthreads();
    if (tid < 32) {
        float s = 0.f, sq = 0.f;
        for (int i = 0; i < 8; i++) {
            s  += partS[i * 32 + tid];
            sq += partQ[i * 32 + tid];
        }
        float mu = s * (1.0f / 256.0f);
        float var = sq * (1.0f / 256.0f) - mu * mu;
        muA[tid] = mu;
        rsA[tid] = rsqrtf(fmaxf(var, 0.0f) + 1e-5f);
    }
    __syncthreads();

    for (int m = 0; m < 2; m++) for (int r = 0; r < 4; r++) {
        int row = m * 16 + qq * 4 + r;
        if (row >= act) continue;
        float mu = muA[row], rs = rsA[row];
        int lr2 = list[base + row];
        for (int j = 0; j < 2; j++) {
            int col = (w + 8 * j) * 16 + cc;
            float y = (acc2[m][j][r] - mu) * rs * gf[j] + btf[j];
            if (out) {
                if (isbf) ((bf16_t*)out)[(size_t)lr2 * 256 + col] = (bf16_t)y;
                else      ((float*)out)[(size_t)lr2 * 256 + col] = y;
            } else {
                ne2[(size_t)(slotBase + lr2) * 256 + col] = (bf16_t)y;
            }
        }
    }
#undef STAGE1
#undef STAGE2
}

extern "C" void kernel_launch(void* const* d_in, const int* in_sizes, int n_in,
                              void* d_out, int out_size, void* d_ws, size_t ws_size,
                              hipStream_t stream) {
    const int* cid    = (const int*)d_in[0];
    const int* opids  = (const int*)d_in[1];
    const int* lch    = (const int*)d_in[2];
    const int* rch    = (const int*)d_in[3];
    const int* tch    = (const int*)d_in[4];
    const int* lvl2   = (const int*)d_in[5];
    const int* lvl1   = (const int*)d_in[6];
    const int* lvl0   = (const int*)d_in[7];
    const void* comp_table = d_in[8];
    const void* op_table   = d_in[9];
    const void* W1b = d_in[10];
    const void* b1b = d_in[11];
    const void* W2b = d_in[12];
    const void* b2b = d_in[13];
    const void* W1t = d_in[14];
    const void* b1t = d_in[15];
    const void* W2t = d_in[16];
    const void* b2t = d_in[17];
    const void* gma = d_in[18];
    const void* bta = d_in[19];

    char* wsp = (char*)d_ws;
    bf16_t* ne2  = (bf16_t*)wsp;                 size_t off = 12582912; // 24576*256*2
    bf16_t* opb  = (bf16_t*)(wsp + off);         off += 8192;           // 16*256*2
    bf16_t* ctb  = (bf16_t*)(wsp + off);         off += 1024000;        // 2000*256*2
    bf16_t* W1bp = (bf16_t*)(wsp + off);         off += 786432;         // 768*512*2
    bf16_t* W1tp = (bf16_t*)(wsp + off);         off += 1048576;        // 1024*512*2
    bf16_t* W2bp = (bf16_t*)(wsp + off);         off += 262144;         // 512*256*2
    bf16_t* W2tp = (bf16_t*)(wsp + off);         off += 262144;
    int* inv   = (int*)(wsp + off);              off += 262144;         // 65536*4
    int* lists = (int*)(wsp + off);              off += 229376;         // 57344*4
    int* cnts  = (int*)(wsp + off);              off += 64;             // total ~16.5 MB
    int* flag  = cnts + 8;

    hipMemsetAsync(cnts, 0, 64, stream);
    hipMemsetAsync(inv, 0xFF, 262144, stream);
    // one merged prep dispatch: detect + conv_op + ctb + pack_w x4 + scan_rows
    prep<<<940, 256, 0, stream>>>(op_table, opb, comp_table, ctb,
                                  W1b, W1bp, W1t, W1tp, W2b, W2bp, W2t, W2tp, flag,
                                  lvl2, lvl1, lvl0, tch, lists, cnts, inv);

    // level 2: lists t @0 / b @16384, cnts slot 0 -> slots base 0
    fused_level<<<513, 512, 0, stream>>>(lists + 0, lists + 16384, cnts + 0, lvl2,
        opids, lch, rch, tch, ne2, opb, comp_table, ctb, cid, inv, flag,
        W1tp, b1t, W2tp, b2t, W1bp, b1b, W2bp, b2b, gma, bta, 0, nullptr);
    // level 1: lists t @32768 / b @40960, cnts slot 1 -> slots base 16384
    fused_level<<<257, 512, 0, stream>>>(lists + 32768, lists + 40960, cnts + 2, lvl1,
        opids, lch, rch, tch, ne2, opb, comp_table, ctb, cid, inv, flag,
        W1tp, b1t, W2tp, b2t, W1bp, b1b, W2bp, b2b, gma, bta, 16384, nullptr);
    // level 0: lists t @49152 / b @53248, cnts slot 2 -> d_out
    fused_level<<<129, 512, 0, stream>>>(lists + 49152, lists + 53248, cnts + 4, lvl0,
        opids, lch, rch, tch, ne2, opb, comp_table, ctb, cid, inv, flag,
        W1tp, b1t, W2tp, b2t, W1bp, b1b, W2bp, b2b, gma, bta, 0, d_out);
}